// Round 7
// baseline (66.528 us; speedup 1.0000x reference)
//
#include <hip/hip_runtime.h>
#include <math.h>

#define BATCH 128
#define HH 256
#define WW 256
#define HW (HH * WW)
#define HW4 (HW / 4)   // 16384 float4 per plane
#define NBLK 512       // persistent blocks (2 per CU x 256 CU), 4 per batch
#define CPB 16         // chunks per block; chunk = 256 float4 per plane
#define NKPT 68
#define FLAG_MAGIC 0x13579BDF

typedef float fx4 __attribute__((ext_vector_type(4)));

__device__ inline double wave_sum64(double v) {
#pragma unroll
    for (int off = 32; off > 0; off >>= 1) v += __shfl_xor(v, off);
    return v;
}

// ---------------------------------------------------------------------------
// Per-batch similarity transform, wave-parallel. Computes RT[12] for batch tb
// and (in the fused kernel) release-publishes it via flags[tb] = MAGIC.
// Math identical to the verified R5 version (absmax 0.03125).
// ---------------------------------------------------------------------------
__device__ void tform_wave(int tb, int lane, const float* __restrict__ Offset,
                           const float* __restrict__ Posmap,
                           const float* __restrict__ meanp,
                           const int* __restrict__ uv, float* __restrict__ RT) {
    const float* offb = Offset + (size_t)tb * 3 * HW;
    const float* dstb = Posmap + (size_t)tb * 3 * HW;
    const bool has1 = lane < (NKPT - 64);

    double s0[3], d0[3], s1[3] = {0, 0, 0}, d1[3] = {0, 0, 0};
    {
        const int q0 = uv[lane * 2 + 0] * WW + uv[lane * 2 + 1];
#pragma unroll
        for (int i = 0; i < 3; i++) {
            s0[i] = (double)offb[(size_t)i * HW + q0] * 6.0 +
                    (double)meanp[(size_t)i * HW + q0];
            d0[i] = (double)dstb[(size_t)i * HW + q0];
        }
        if (has1) {
            const int k1 = lane + 64;
            const int q1 = uv[k1 * 2 + 0] * WW + uv[k1 * 2 + 1];
#pragma unroll
            for (int i = 0; i < 3; i++) {
                s1[i] = (double)offb[(size_t)i * HW + q1] * 6.0 +
                        (double)meanp[(size_t)i * HW + q1];
                d1[i] = (double)dstb[(size_t)i * HW + q1];
            }
        }
    }

    double s33[3], d33[3];
#pragma unroll
    for (int i = 0; i < 3; i++) {
        s33[i] = __shfl(s0[i], 33);
        d33[i] = __shfl(d0[i], 33);
    }

    double ns0 = 0, nd0 = 0, ns1 = 0, nd1 = 0;
    double ssum[3], dsum[3], P[3][3];
#pragma unroll
    for (int i = 0; i < 3; i++) {
        double es = s0[i] - s33[i], ed = d0[i] - d33[i];
        ns0 += es * es;
        nd0 += ed * ed;
        es = s1[i] - s33[i];
        ed = d1[i] - d33[i];
        ns1 += es * es;
        nd1 += ed * ed;
        ssum[i] = s0[i] + s1[i];
        dsum[i] = d0[i] + d1[i];
#pragma unroll
        for (int j = 0; j < 3; j++) P[i][j] = s0[i] * d0[j] + s1[i] * d1[j];
    }
    double sd1p = sqrt(ns0) + (has1 ? sqrt(ns1) : 0.0);
    double sd2p = sqrt(nd0) + (has1 ? sqrt(nd1) : 0.0);

    const double sd1 = wave_sum64(sd1p);
    const double sd2 = wave_sum64(sd2p);
#pragma unroll
    for (int i = 0; i < 3; i++) {
        ssum[i] = wave_sum64(ssum[i]);
        dsum[i] = wave_sum64(dsum[i]);
    }
#pragma unroll
    for (int i = 0; i < 3; i++)
#pragma unroll
        for (int j = 0; j < 3; j++) P[i][j] = wave_sum64(P[i][j]);

    if (lane != 0) return;

    const double s = sd2 / sd1;
    double sbar[3], dbar[3];
#pragma unroll
    for (int i = 0; i < 3; i++) {
        sbar[i] = ssum[i] / NKPT;
        dbar[i] = dsum[i] / NKPT;
    }
    double Hm[3][3];
    for (int i = 0; i < 3; i++)
        for (int j = 0; j < 3; j++)
            Hm[i][j] = P[i][j] - (double)NKPT * sbar[i] * dbar[j];

    double A[3][3];
    for (int i = 0; i < 3; i++)
        for (int j = 0; j < 3; j++) {
            double acc = 0;
            for (int kk = 0; kk < 3; kk++) acc += Hm[kk][i] * Hm[kk][j];
            A[i][j] = acc;
        }

    double V[3][3] = {{1, 0, 0}, {0, 1, 0}, {0, 0, 1}};
    for (int sweep = 0; sweep < 12; ++sweep) {
        double off = fabs(A[0][1]) + fabs(A[0][2]) + fabs(A[1][2]);
        double diag = fabs(A[0][0]) + fabs(A[1][1]) + fabs(A[2][2]);
        if (off <= diag * 1e-15) break;
        for (int pp = 0; pp < 2; pp++)
            for (int q = pp + 1; q < 3; q++) {
                double apq = A[pp][q];
                if (fabs(apq) < 1e-300) continue;
                double theta = (A[q][q] - A[pp][pp]) / (2.0 * apq);
                double t = (theta >= 0.0 ? 1.0 : -1.0) /
                           (fabs(theta) + sqrt(theta * theta + 1.0));
                double cc = 1.0 / sqrt(t * t + 1.0);
                double sn = t * cc;
                A[pp][pp] -= t * apq;
                A[q][q] += t * apq;
                A[pp][q] = 0.0;
                A[q][pp] = 0.0;
                int r = 3 - pp - q;
                double arp = A[r][pp], arq = A[r][q];
                A[r][pp] = A[pp][r] = cc * arp - sn * arq;
                A[r][q] = A[q][r] = sn * arp + cc * arq;
#pragma unroll
                for (int rr = 0; rr < 3; rr++) {
                    double vrp = V[rr][pp], vrq = V[rr][q];
                    V[rr][pp] = cc * vrp - sn * vrq;
                    V[rr][q] = sn * vrp + cc * vrq;
                }
            }
    }
    double isig[3];
#pragma unroll
    for (int i = 0; i < 3; i++) {
        double l = A[i][i];
        if (l < 1e-30) l = 1e-30;
        isig[i] = 1.0 / sqrt(l);
    }
    double Wm[3][3];
    for (int i = 0; i < 3; i++)
        for (int j = 0; j < 3; j++) {
            double acc = 0;
            for (int kk = 0; kk < 3; kk++) acc += V[i][kk] * V[j][kk] * isig[kk];
            Wm[i][j] = acc;
        }
    double R[3][3];
    for (int i = 0; i < 3; i++)
        for (int j = 0; j < 3; j++) {
            double acc = 0;
            for (int kk = 0; kk < 3; kk++) acc += Wm[i][kk] * Hm[j][kk];
            R[i][j] = acc;
        }

    float* rt = RT + tb * 12;
    for (int j = 0; j < 3; j++) {
        for (int i = 0; i < 3; i++) rt[j * 3 + i] = (float)(R[j][i] * s);
        double tj = dbar[j];
        for (int i = 0; i < 3; i++) tj -= s * sbar[i] * R[j][i];
        rt[9 + j] = (float)tj;
    }
}

// ---------------------------------------------------------------------------
// Fused cooperative kernel, 512 persistent blocks. Blocks 0..127: wave 0
// computes batch blk's transform, then release-publishes flags[blk]=MAGIC.
// Every block acquire-spins on its apply-batch's flag (co-residency is
// guaranteed by the cooperative launch), then streams 16 chunks with
// next-chunk prefetch and nontemporal stores.
// ---------------------------------------------------------------------------
__global__ __launch_bounds__(256, 4) void fused_coop(
    const float* __restrict__ Offset, const float* __restrict__ Posmap,
    const float* __restrict__ meanp, const int* __restrict__ uv,
    float* __restrict__ Out, float* __restrict__ WS) {
    float* RT = WS;                       // 128*12 floats
    int* flags = (int*)(WS + BATCH * 12); // 128 ints

    const int blk = blockIdx.x;
    const int tid = threadIdx.x;
    const int ab = blk >> 2;         // apply batch (4 blocks per batch)
    const int c0 = (blk & 3) * CPB;  // first chunk-in-batch (of 64)
    const size_t base = (size_t)ab * 3 * HW4;

    const fx4* Off4 = (const fx4*)Offset;
    const fx4* Mean4 = (const fx4*)meanp;
    fx4* Out4 = (fx4*)Out;

    // Prefetch first chunk before tform so HBM latency hides under it.
    const int p0 = c0 * 256 + tid;
    fx4 co0 = Off4[base + p0];
    fx4 co1 = Off4[base + HW4 + p0];
    fx4 co2 = Off4[base + 2 * HW4 + p0];

    // Blocks 0..127: compute batch blk's transform on wave 0, publish.
    if (blk < BATCH && tid < 64) {
        tform_wave(blk, tid, Offset, Posmap, meanp, uv, RT);
        if (tid == 0) {
            __threadfence();  // device-scope release of RT
            __hip_atomic_store(&flags[blk], FLAG_MAGIC, __ATOMIC_RELEASE,
                               __HIP_MEMORY_SCOPE_AGENT);
        }
    }

    // Acquire the apply batch's transform.
    if (tid == 0) {
        while (__hip_atomic_load(&flags[ab], __ATOMIC_ACQUIRE,
                                 __HIP_MEMORY_SCOPE_AGENT) != FLAG_MAGIC) {
            __builtin_amdgcn_s_sleep(8);
        }
    }
    __syncthreads();

    const float* rt = RT + ab * 12;
    const float r00 = rt[0], r01 = rt[1], r02 = rt[2];
    const float r10 = rt[3], r11 = rt[4], r12 = rt[5];
    const float r20 = rt[6], r21 = rt[7], r22 = rt[8];
    const float t0 = rt[9], t1 = rt[10], t2 = rt[11];

#pragma unroll
    for (int c = 0; c < CPB; ++c) {
        const int pc = (c0 + c) * 256 + tid;
        fx4 n0, n1, n2;
        if (c < CPB - 1) {
            const int pn = pc + 256;
            n0 = Off4[base + pn];
            n1 = Off4[base + HW4 + pn];
            n2 = Off4[base + 2 * HW4 + pn];
        }
        fx4 m0 = Mean4[pc];
        fx4 m1 = Mean4[HW4 + pc];
        fx4 m2 = Mean4[2 * HW4 + pc];

        fx4 y0, y1, y2;
#pragma unroll
        for (int e = 0; e < 4; e++) {
            float x0 = fmaf(co0[e], 6.0f, m0[e]);
            float x1 = fmaf(co1[e], 6.0f, m1[e]);
            float x2 = fmaf(co2[e], 6.0f, m2[e]);
            y0[e] = fmaf(x0, r00, fmaf(x1, r01, fmaf(x2, r02, t0)));
            y1[e] = fmaf(x0, r10, fmaf(x1, r11, fmaf(x2, r12, t1)));
            y2[e] = fmaf(x0, r20, fmaf(x1, r21, fmaf(x2, r22, t2)));
        }
        __builtin_nontemporal_store(y0, &Out4[base + pc]);
        __builtin_nontemporal_store(y1, &Out4[base + HW4 + pc]);
        __builtin_nontemporal_store(y2, &Out4[base + 2 * HW4 + pc]);

        if (c < CPB - 1) {
            co0 = n0;
            co1 = n1;
            co2 = n2;
        }
    }
}

// --------------------- Fallback path (proven R5, 43.7 us) -------------------
__global__ __launch_bounds__(64, 1) void tform_kernel(
    const float* __restrict__ Offset, const float* __restrict__ Posmap,
    const float* __restrict__ meanp, const int* __restrict__ uv,
    float* __restrict__ RT) {
    tform_wave(blockIdx.x, threadIdx.x, Offset, Posmap, meanp, uv, RT);
}

__global__ __launch_bounds__(256) void apply_kernel(
    const fx4* __restrict__ Off, const fx4* __restrict__ Mean,
    const float* __restrict__ RT, fx4* __restrict__ Out) {
    const int CH = HW4 / 256;  // 64
    const int b = blockIdx.x / CH;
    const int p = (blockIdx.x % CH) * 256 + threadIdx.x;

    const size_t base = (size_t)b * 3 * HW4;
    fx4 o0 = Off[base + p];
    fx4 o1 = Off[base + HW4 + p];
    fx4 o2 = Off[base + 2 * HW4 + p];
    fx4 m0 = Mean[p];
    fx4 m1 = Mean[HW4 + p];
    fx4 m2 = Mean[2 * HW4 + p];

    const float* rt = RT + b * 12;
    const float r00 = rt[0], r01 = rt[1], r02 = rt[2];
    const float r10 = rt[3], r11 = rt[4], r12 = rt[5];
    const float r20 = rt[6], r21 = rt[7], r22 = rt[8];
    const float t0 = rt[9], t1 = rt[10], t2 = rt[11];

    fx4 y0, y1, y2;
#pragma unroll
    for (int c = 0; c < 4; c++) {
        float x0 = fmaf(o0[c], 6.0f, m0[c]);
        float x1 = fmaf(o1[c], 6.0f, m1[c]);
        float x2 = fmaf(o2[c], 6.0f, m2[c]);
        y0[c] = fmaf(x0, r00, fmaf(x1, r01, fmaf(x2, r02, t0)));
        y1[c] = fmaf(x0, r10, fmaf(x1, r11, fmaf(x2, r12, t1)));
        y2[c] = fmaf(x0, r20, fmaf(x1, r21, fmaf(x2, r22, t2)));
    }
    __builtin_nontemporal_store(y0, &Out[base + p]);
    __builtin_nontemporal_store(y1, &Out[base + HW4 + p]);
    __builtin_nontemporal_store(y2, &Out[base + 2 * HW4 + p]);
}

extern "C" void kernel_launch(void* const* d_in, const int* in_sizes, int n_in,
                              void* d_out, int out_size, void* d_ws,
                              size_t ws_size, hipStream_t stream) {
    const float* Offset = (const float*)d_in[0];
    const float* Posmap = (const float*)d_in[1];
    const float* meanp = (const float*)d_in[2];
    const int* uv = (const int*)d_in[3];
    float* out = (float*)d_out;
    float* WS = (float*)d_ws;  // 128*12 RT floats + 128 flag ints

    void* args[] = {(void*)&Offset, (void*)&Posmap, (void*)&meanp,
                    (void*)&uv,     (void*)&out,    (void*)&WS};
    hipError_t err = hipLaunchCooperativeKernel(
        (const void*)fused_coop, dim3(NBLK), dim3(256), args, 0, stream);
    if (err != hipSuccess) {
        (void)hipGetLastError();  // clear sticky error, use fallback path
        tform_kernel<<<BATCH, 64, 0, stream>>>(Offset, Posmap, meanp, uv, WS);
        apply_kernel<<<BATCH * (HW4 / 256), 256, 0, stream>>>(
            (const fx4*)Offset, (const fx4*)meanp, WS, (fx4*)out);
    }
}